// Round 6
// baseline (77.638 us; speedup 1.0000x reference)
//
#include <hip/hip_runtime.h>
#include <cstddef>
#include <cstdint>

typedef __attribute__((ext_vector_type(8))) _Float16 f16x8;
typedef __attribute__((ext_vector_type(4))) float f32x4;

constexpr int S = 128;
constexpr int H = 64;
constexpr int A = 8;
constexpr float GAMMA = 0.98f;
constexpr float EPS_CLIP = 0.1f;

__device__ __forceinline__ float swishf(float x) {
    return x * __builtin_amdgcn_rcpf(1.0f + __expf(-x));
}
__device__ __forceinline__ f32x4 mfmaf(f16x8 a, f16x8 b, f32x4 c) {
    return __builtin_amdgcn_mfma_f32_16x16x32_f16(a, b, c, 0, 0, 0);
}

// Pinned async load: global_load_dwordx4 via SGPR base + 32b voffset + literal
// imm. asm volatile + "memory" clobber => compiler cannot sink, split, or
// insert its own waits for these; WE own the vmcnt discipline.
#define GLD(dst, voff, IMM)                                          \
    asm volatile("global_load_dwordx4 %0, %1, %2 offset:" IMM       \
                 : "=v"(dst) : "v"(voff), "s"(xp) : "memory")

// Grid = 2*nbf blocks of 512 threads (8 waves). Blocks [0,nbf): pass 0 over s
// (writes v_s and pi_a). Blocks [nbf,2nbf): pass 1 over s' (writes v_sp).
// r4 structure + asm-pinned x-loads:
//   dt0's 16 dwordx4 issued BEFORE weight staging (latency hidden under
//   staging; the pre-barrier vmcnt(0) drains them for free).
//   dt1's 16 issued right after dt0's cvt -> in flight across dt0's whole
//   MFMA/transpose chain. s_waitcnt vmcnt(0)+sched_barrier(0) before each cvt
//   (sched_barrier stops hipcc hoisting reg-only consumers above the wait).
//   All global stores deferred to after the loop (ahk regs) so vmcnt(0) at
//   dt1 counts ONLY our 16 loads.
// A-frag (16x32 f16): lane l holds A[l&15][(l>>4)*8 + j].
// B-frag: lane l holds B[(l>>4)*8 + j][l&15].  C/D: col=lane&15, row=(lane>>4)*4+reg.
__global__ __launch_bounds__(512, 2) void ppo_fwd(
    const float* __restrict__ s, const float* __restrict__ sp,
    const int* __restrict__ aidx,
    const float* __restrict__ W1, const float* __restrict__ b1,
    const float* __restrict__ W2, const float* __restrict__ b2,
    const float* __restrict__ Wa, const float* __restrict__ ba,
    const float* __restrict__ Wc, const float* __restrict__ bc,
    float* __restrict__ ws_vs, float* __restrict__ ws_pia,
    float* __restrict__ ws_vsp, int nbf)
{
    __shared__ f16x8 sW1[16][64];                        // 16 KB
    __shared__ f16x8 sW2[8][64];                         //  8 KB
    __shared__ f16x8 sWh[2][64];                         //  2 KB
    __shared__ __align__(16) _Float16 hbuf[8][16 * 72];  // 18 KB
    __shared__ float hs[8][16 * 11];                     //  5.5 KB

    const int tid = threadIdx.x;
    const int pass = (blockIdx.x >= (unsigned)nbf) ? 1 : 0;
    const int rb = blockIdx.x - pass * nbf;
    const float* __restrict__ xp = pass ? sp : s;

    const int w = tid >> 6, l = tid & 63, g = l >> 4, n15 = l & 15;
    const int wbase = rb * 512 + w * 64;

    // byte offset of (row wbase+n15, col g*8) : row stride 512 B
    const unsigned vbase = (unsigned)(wbase + n15) * 512u + (unsigned)g * 32u;
    const unsigned voffA = vbase;             // dt0 tile0 (rows +0)
    const unsigned voffB = vbase + 8192u;     // dt0 tile1 (rows +16)

    // ---- issue dt0's 16 loads BEFORE staging (pinned) ----
    float4 raw[16];
    GLD(raw[0],  voffA, "0");   GLD(raw[1],  voffA, "16");
    GLD(raw[2],  voffA, "128"); GLD(raw[3],  voffA, "144");
    GLD(raw[4],  voffA, "256"); GLD(raw[5],  voffA, "272");
    GLD(raw[6],  voffA, "384"); GLD(raw[7],  voffA, "400");
    GLD(raw[8],  voffB, "0");   GLD(raw[9],  voffB, "16");
    GLD(raw[10], voffB, "128"); GLD(raw[11], voffB, "144");
    GLD(raw[12], voffB, "256"); GLD(raw[13], voffB, "272");
    GLD(raw[14], voffB, "384"); GLD(raw[15], voffB, "400");

    // ---- per-row scalars, hidden under staging; drained by the barrier ----
    float b1r[4], b2r[4];
    #pragma unroll
    for (int nt = 0; nt < 4; ++nt) { b1r[nt] = b1[nt * 16 + n15]; b2r[nt] = b2[nt * 16 + n15]; }
    const float bhr = (n15 == 0) ? bc[0] : ((n15 <= 8) ? ba[n15 - 1] : 0.0f);
    int act[2][2] = {{0, 0}, {0, 0}};
    if (pass == 0 && l < 16) {
        #pragma unroll
        for (int mt2 = 0; mt2 < 2; ++mt2) {
            act[mt2][0] = aidx[wbase + mt2 * 32 + l];
            act[mt2][1] = aidx[wbase + mt2 * 32 + 16 + l];
        }
    }

    // ---- pack weight fragments (single fp16 term) ----
    for (int idx = tid; idx < 16 * 64; idx += 512) {
        int f = idx >> 6, ll = idx & 63;
        int nt = f >> 2, kk = f & 3;
        int gg = ll >> 4, col = nt * 16 + (ll & 15);
        f16x8 v;
        #pragma unroll
        for (int j = 0; j < 8; ++j)
            v[j] = (_Float16)W1[(kk * 32 + gg * 8 + j) * H + col];
        sW1[f][ll] = v;
    }
    for (int idx = tid; idx < 8 * 64; idx += 512) {
        int f = idx >> 6, ll = idx & 63;
        int nt = f >> 1, kk = f & 1;
        int gg = ll >> 4, col = nt * 16 + (ll & 15);
        f16x8 v;
        #pragma unroll
        for (int j = 0; j < 8; ++j)
            v[j] = (_Float16)W2[(kk * 32 + gg * 8 + j) * H + col];
        sW2[f][ll] = v;
    }
    for (int idx = tid; idx < 2 * 64; idx += 512) {
        int kk = idx >> 6, ll = idx & 63;
        int gg = ll >> 4, q = ll & 15;
        f16x8 v;
        #pragma unroll
        for (int j = 0; j < 8; ++j) {
            int k = kk * 32 + gg * 8 + j;
            v[j] = (_Float16)((q == 0) ? Wc[k] : ((q <= 8) ? Wa[k * A + (q - 1)] : 0.0f));
        }
        sWh[kk][ll] = v;
    }
    __syncthreads();

    _Float16* hb = hbuf[w];
    float* hsw = hs[w];

    f32x4 ahk[2][2];   // head outputs kept in regs; all stores after the loop

    #pragma unroll
    for (int mt2 = 0; mt2 < 2; ++mt2) {
        // ---- wait for this dt's pinned loads; fence against hoisting ----
        asm volatile("s_waitcnt vmcnt(0)" ::: "memory");
        __builtin_amdgcn_sched_barrier(0);

        // ---- raw -> fp16 A-frags ----
        f16x8 ax[2][4];   // [tile][kk]
        #pragma unroll
        for (int tile = 0; tile < 2; ++tile)
            #pragma unroll
            for (int kk = 0; kk < 4; ++kk) {
                float4 v0 = raw[tile * 8 + kk * 2];
                float4 v1 = raw[tile * 8 + kk * 2 + 1];
                f16x8 a;
                a[0] = (_Float16)v0.x; a[1] = (_Float16)v0.y;
                a[2] = (_Float16)v0.z; a[3] = (_Float16)v0.w;
                a[4] = (_Float16)v1.x; a[5] = (_Float16)v1.y;
                a[6] = (_Float16)v1.z; a[7] = (_Float16)v1.w;
                ax[tile][kk] = a;
            }

        // ---- issue dt1's 16 loads: in flight through dt0's whole chain ----
        if (mt2 == 0) {
            const unsigned voffC = vbase + 16384u;   // rows +32
            const unsigned voffD = vbase + 24576u;   // rows +48
            GLD(raw[0],  voffC, "0");   GLD(raw[1],  voffC, "16");
            GLD(raw[2],  voffC, "128"); GLD(raw[3],  voffC, "144");
            GLD(raw[4],  voffC, "256"); GLD(raw[5],  voffC, "272");
            GLD(raw[6],  voffC, "384"); GLD(raw[7],  voffC, "400");
            GLD(raw[8],  voffD, "0");   GLD(raw[9],  voffD, "16");
            GLD(raw[10], voffD, "128"); GLD(raw[11], voffD, "144");
            GLD(raw[12], voffD, "256"); GLD(raw[13], voffD, "272");
            GLD(raw[14], voffD, "384"); GLD(raw[15], voffD, "400");
        }

        // ---- layer 1: [16x128]@[128x64], both tiles share each W-frag read ----
        f32x4 acc[2][4];
        #pragma unroll
        for (int tile = 0; tile < 2; ++tile)
            #pragma unroll
            for (int nt = 0; nt < 4; ++nt)
                acc[tile][nt] = (f32x4){b1r[nt], b1r[nt], b1r[nt], b1r[nt]};
        #pragma unroll
        for (int nt = 0; nt < 4; ++nt)
            #pragma unroll
            for (int kk = 0; kk < 4; ++kk) {
                f16x8 bw = sW1[nt * 4 + kk][l];
                acc[0][nt] = mfmaf(ax[0][kk], bw, acc[0][nt]);
                acc[1][nt] = mfmaf(ax[1][kk], bw, acc[1][nt]);
            }

        // ---- swish + LDS transpose (C layout -> A layout), per tile ----
        f16x8 a2[2][2];
        #pragma unroll
        for (int tile = 0; tile < 2; ++tile) {
            #pragma unroll
            for (int nt = 0; nt < 4; ++nt)
                #pragma unroll
                for (int rj = 0; rj < 4; ++rj)
                    hb[(g * 4 + rj) * 72 + nt * 16 + n15] =
                        (_Float16)swishf(acc[tile][nt][rj]);
            #pragma unroll
            for (int kk = 0; kk < 2; ++kk)
                a2[tile][kk] = *reinterpret_cast<f16x8*>(&hb[n15 * 72 + kk * 32 + g * 8]);
        }

        // ---- layer 2: [16x64]@[64x64] ----
        f32x4 acc2[2][4];
        #pragma unroll
        for (int tile = 0; tile < 2; ++tile)
            #pragma unroll
            for (int nt = 0; nt < 4; ++nt)
                acc2[tile][nt] = (f32x4){b2r[nt], b2r[nt], b2r[nt], b2r[nt]};
        #pragma unroll
        for (int nt = 0; nt < 4; ++nt)
            #pragma unroll
            for (int kk = 0; kk < 2; ++kk) {
                f16x8 bw = sW2[nt * 2 + kk][l];
                acc2[0][nt] = mfmaf(a2[0][kk], bw, acc2[0][nt]);
                acc2[1][nt] = mfmaf(a2[1][kk], bw, acc2[1][nt]);
            }

        // ---- transpose again -> head A-frags ----
        f16x8 a3[2][2];
        #pragma unroll
        for (int tile = 0; tile < 2; ++tile) {
            #pragma unroll
            for (int nt = 0; nt < 4; ++nt)
                #pragma unroll
                for (int rj = 0; rj < 4; ++rj)
                    hb[(g * 4 + rj) * 72 + nt * 16 + n15] =
                        (_Float16)swishf(acc2[tile][nt][rj]);
            #pragma unroll
            for (int kk = 0; kk < 2; ++kk)
                a3[tile][kk] = *reinterpret_cast<f16x8*>(&hb[n15 * 72 + kk * 32 + g * 8]);
        }

        // ---- head: [16x64]@[64x16] (col0=v, col1..8=logits) ----
        f32x4 ah[2] = {(f32x4){bhr, bhr, bhr, bhr}, (f32x4){bhr, bhr, bhr, bhr}};
        #pragma unroll
        for (int kk = 0; kk < 2; ++kk) {
            f16x8 bw = sWh[kk][l];
            ah[0] = mfmaf(a3[0][kk], bw, ah[0]);
            ah[1] = mfmaf(a3[1][kk], bw, ah[1]);
        }
        ahk[mt2][0] = ah[0];
        ahk[mt2][1] = ah[1];
    }

    // ---- deferred epilogue: all global stores after the load pipeline ----
    if (pass == 1) {
        // v_sp lives in col 0 = lanes with n15==0; rows g*4+rj
        #pragma unroll
        for (int mt2 = 0; mt2 < 2; ++mt2)
            #pragma unroll
            for (int tile = 0; tile < 2; ++tile)
                if (n15 == 0) {
                    #pragma unroll
                    for (int rj = 0; rj < 4; ++rj)
                        ws_vsp[wbase + mt2 * 32 + tile * 16 + g * 4 + rj] = ahk[mt2][tile][rj];
                }
    } else {
        #pragma unroll
        for (int mt2 = 0; mt2 < 2; ++mt2)
            #pragma unroll
            for (int tile = 0; tile < 2; ++tile) {
                if (n15 <= 8) {
                    #pragma unroll
                    for (int rj = 0; rj < 4; ++rj)
                        hsw[(g * 4 + rj) * 11 + n15] = ahk[mt2][tile][rj];
                }
                if (l < 16) {
                    float vs = hsw[l * 11 + 0];
                    float lgq[A];
                    float m = -1e30f;
                    #pragma unroll
                    for (int q = 0; q < A; ++q) {
                        lgq[q] = hsw[l * 11 + 1 + q];
                        m = fmaxf(m, lgq[q]);
                    }
                    float den = 0.f, num = 0.f;
                    #pragma unroll
                    for (int q = 0; q < A; ++q) {
                        float e = __expf(lgq[q] - m);
                        den += e;
                        num = (q == act[mt2][tile]) ? e : num;
                    }
                    int t = wbase + mt2 * 32 + tile * 16 + l;
                    ws_vs[t]  = vs;
                    ws_pia[t] = num / den;
                }
            }
    }
}

// Per-row epilogue: out[t] = -min(surr1,surr2); huber partials per block.
__global__ __launch_bounds__(256) void ppo_epi(
    const float* __restrict__ r, const float* __restrict__ done,
    const float* __restrict__ prob_a,
    const float* __restrict__ ws_vs, const float* __restrict__ ws_pia,
    const float* __restrict__ ws_vsp,
    float* __restrict__ out, float* __restrict__ partial, int Ttot)
{
    __shared__ float sred[256];
    const int tid = threadIdx.x;
    const int t = blockIdx.x * 256 + tid;

    float he = 0.f;
    if (t < Ttot) {
        float vs  = ws_vs[t];
        float vsp = ws_vsp[t];
        float rr  = r[t];
        float dm  = done[t];
        float ratio = ws_pia[t] / prob_a[t];

        float td_target = fmaf(GAMMA * dm, vsp, rr);
        float delta     = rr + GAMMA * vsp - vs;
        float s1 = ratio * delta;
        float rcl = fminf(fmaxf(ratio, 1.0f - EPS_CLIP), 1.0f + EPS_CLIP);
        float s2 = rcl * delta;
        out[t] = -fminf(s1, s2);

        float err = td_target - vs;
        float ae = fabsf(err);
        he = (ae <= 1.0f) ? (0.5f * err * err) : (ae - 0.5f);
    }

    sred[tid] = he;
    __syncthreads();
    #pragma unroll
    for (int off = 128; off > 0; off >>= 1) {
        if (tid < off) sred[tid] += sred[tid + off];
        __syncthreads();
    }
    if (tid == 0) partial[blockIdx.x] = sred[0];
}

// Every block reduces the (L2-resident) partial array to the huber mean, then
// adds it to its own slice of out. Replaces the reduce+add launch pair.
__global__ __launch_bounds__(256) void ppo_finish(
    const float* __restrict__ partial, int nparts, float invT,
    float4* __restrict__ out4, int n4)
{
    __shared__ float sred[256];
    const int tid = threadIdx.x;
    float v = 0.f;
    for (int i = tid; i < nparts; i += 256) v += partial[i];
    sred[tid] = v;
    __syncthreads();
    #pragma unroll
    for (int off = 128; off > 0; off >>= 1) {
        if (tid < off) sred[tid] += sred[tid + off];
        __syncthreads();
    }
    const float m = sred[0] * invT;
    const int i = blockIdx.x * 256 + tid;
    if (i < n4) {
        float4 o = out4[i];
        o.x += m; o.y += m; o.z += m; o.w += m;
        out4[i] = o;
    }
}

extern "C" void kernel_launch(void* const* d_in, const int* in_sizes, int n_in,
                              void* d_out, int out_size, void* d_ws, size_t ws_size,
                              hipStream_t stream)
{
    const float* s      = (const float*)d_in[0];
    const float* sp     = (const float*)d_in[1];
    const float* r      = (const float*)d_in[2];
    const float* done   = (const float*)d_in[3];
    const float* prob_a = (const float*)d_in[4];
    const int*   a      = (const int*)d_in[5];
    const float* W1     = (const float*)d_in[6];
    const float* b1     = (const float*)d_in[7];
    const float* W2     = (const float*)d_in[8];
    const float* b2     = (const float*)d_in[9];
    const float* Wa     = (const float*)d_in[10];
    const float* ba     = (const float*)d_in[11];
    const float* Wc     = (const float*)d_in[12];
    const float* bc     = (const float*)d_in[13];

    float* out = (float*)d_out;
    float* ws  = (float*)d_ws;

    const int Ttot = in_sizes[0] / S;              // 262144
    const int nbf  = Ttot / 512;                   // 512 fwd row-blocks (512 rows each)
    const int nbe  = Ttot / 256;                   // 1024 epi blocks

    float* ws_vs  = ws;
    float* ws_pia = ws + Ttot;
    float* ws_vsp = ws + 2 * (size_t)Ttot;
    float* partial = ws + 3 * (size_t)Ttot;        // nbe floats

    ppo_fwd<<<2 * nbf, 512, 0, stream>>>(s, sp, a, W1, b1, W2, b2, Wa, ba, Wc, bc,
                                         ws_vs, ws_pia, ws_vsp, nbf);
    ppo_epi<<<nbe, 256, 0, stream>>>(r, done, prob_a, ws_vs, ws_pia, ws_vsp,
                                     out, partial, Ttot);

    const int n4 = Ttot / 4;
    ppo_finish<<<(n4 + 255) / 256, 256, 0, stream>>>(partial, nbe,
                                                     1.0f / (float)Ttot,
                                                     (float4*)out, n4);
}

// Round 7
// 71.672 us; speedup vs baseline: 1.0832x; 1.0832x over previous
//
#include <hip/hip_runtime.h>
#include <cstddef>
#include <cstdint>

typedef __attribute__((ext_vector_type(8))) _Float16 f16x8;
typedef __attribute__((ext_vector_type(4))) float f32x4;

constexpr int S = 128;
constexpr int H = 64;
constexpr int A = 8;
constexpr float GAMMA = 0.98f;
constexpr float EPS_CLIP = 0.1f;

__device__ __forceinline__ float swishf(float x) {
    return x * __builtin_amdgcn_rcpf(1.0f + __expf(-x));
}
__device__ __forceinline__ f32x4 mfmaf(f16x8 a, f16x8 b, f32x4 c) {
    return __builtin_amdgcn_mfma_f32_16x16x32_f16(a, b, c, 0, 0, 0);
}
// pack two f32 -> one u32 of two f16 (lo, hi)
__device__ __forceinline__ unsigned pk2(float lo, float hi) {
    union { _Float16 f[2]; unsigned u; } x;
    x.f[0] = (_Float16)lo; x.f[1] = (_Float16)hi;
    return x.u;
}

// Grid = 2*nbf blocks of 512 threads (8 waves). Blocks [0,nbf): pass 0 over s
// (writes v_s and pi_a). Blocks [nbf,2nbf): pass 1 over s' (writes v_sp).
// SWAPPED-OPERAND formulation: every layer computes Y^T = W^T @ X^T.
//  - weight staging is UNCHANGED (the old B-frag packing == A-frag of W^T).
//  - x loads are UNCHANGED (old A-frag data == B-frag of x^T).
//  - the inter-layer transpose is now an in-register lane permutation
//    (pk2 + __shfl) instead of a dependent ds_write->wait->ds_read chain:
//    dest lane l, frag word i <- lane ((2g+(i>>1))&3)*16+n15 of acc tile
//    2kk2+(g>>1). No hbuf, no hs => LDS 26.6 KB, no barriers after staging.
// C/D layout reminder (D=Y^T): lane l reg r = Y^T[tile*16 + 4g + r][l&15]
//  => head col 0 (v) sits at lanes 0..15 reg 0, coalesced.
__global__ __launch_bounds__(512, 2) void ppo_fwd(
    const float* __restrict__ s, const float* __restrict__ sp,
    const int* __restrict__ aidx,
    const float* __restrict__ W1, const float* __restrict__ b1,
    const float* __restrict__ W2, const float* __restrict__ b2,
    const float* __restrict__ Wa, const float* __restrict__ ba,
    const float* __restrict__ Wc, const float* __restrict__ bc,
    float* __restrict__ ws_vs, float* __restrict__ ws_pia,
    float* __restrict__ ws_vsp, int nbf)
{
    __shared__ f16x8 sW1[16][64];                        // 16 KB
    __shared__ f16x8 sW2[8][64];                         //  8 KB
    __shared__ f16x8 sWh[2][64];                         //  2 KB

    const int tid = threadIdx.x;
    const int pass = (blockIdx.x >= (unsigned)nbf) ? 1 : 0;
    const int rb = blockIdx.x - pass * nbf;
    const float* __restrict__ x = pass ? sp : s;

    const int l = tid & 63, g = l >> 4, n15 = l & 15;
    const int wbase = rb * 512 + (tid >> 6) * 64;

    int act[2][2] = {{0, 0}, {0, 0}};
    if (pass == 0 && l < 16) {
        #pragma unroll
        for (int mt2 = 0; mt2 < 2; ++mt2) {
            act[mt2][0] = aidx[wbase + mt2 * 32 + l];
            act[mt2][1] = aidx[wbase + mt2 * 32 + 16 + l];
        }
    }

    // ---- pack weight fragments (unchanged packing == A-frags of W^T) ----
    for (int idx = tid; idx < 16 * 64; idx += 512) {
        int f = idx >> 6, ll = idx & 63;
        int nt = f >> 2, kk = f & 3;
        int gg = ll >> 4, col = nt * 16 + (ll & 15);
        f16x8 v;
        #pragma unroll
        for (int j = 0; j < 8; ++j)
            v[j] = (_Float16)W1[(kk * 32 + gg * 8 + j) * H + col];
        sW1[f][ll] = v;
    }
    for (int idx = tid; idx < 8 * 64; idx += 512) {
        int f = idx >> 6, ll = idx & 63;
        int nt = f >> 1, kk = f & 1;
        int gg = ll >> 4, col = nt * 16 + (ll & 15);
        f16x8 v;
        #pragma unroll
        for (int j = 0; j < 8; ++j)
            v[j] = (_Float16)W2[(kk * 32 + gg * 8 + j) * H + col];
        sW2[f][ll] = v;
    }
    for (int idx = tid; idx < 2 * 64; idx += 512) {
        int kk = idx >> 6, ll = idx & 63;
        int gg = ll >> 4, q = ll & 15;
        f16x8 v;
        #pragma unroll
        for (int j = 0; j < 8; ++j) {
            int k = kk * 32 + gg * 8 + j;
            v[j] = (_Float16)((q == 0) ? Wc[k] : ((q <= 8) ? Wa[k * A + (q - 1)] : 0.0f));
        }
        sWh[kk][ll] = v;
    }
    __syncthreads();

    // ---- biases indexed by D-row = output column = {nt*16,} 4g + r ----
    float4 b1q[4], b2q[4];
    #pragma unroll
    for (int nt = 0; nt < 4; ++nt) {
        b1q[nt] = *reinterpret_cast<const float4*>(b1 + nt * 16 + g * 4);
        b2q[nt] = *reinterpret_cast<const float4*>(b2 + nt * 16 + g * 4);
    }
    f32x4 bhq;
    #pragma unroll
    for (int r = 0; r < 4; ++r) {
        int col = g * 4 + r;
        bhq[r] = (col == 0) ? bc[0] : ((col <= 8) ? ba[col - 1] : 0.0f);
    }

    #pragma unroll
    for (int mt2 = 0; mt2 < 2; ++mt2) {
        const int t0 = wbase + mt2 * 32;

        // ---- load x rows -> B-frags of x^T (identical bytes to old A-frags) ----
        f16x8 ax[2][4];   // [tile][kk]
        #pragma unroll
        for (int tile = 0; tile < 2; ++tile) {
            const float* row = x + (size_t)(t0 + tile * 16 + n15) * S + g * 8;
            #pragma unroll
            for (int kk = 0; kk < 4; ++kk) {
                float4 v0 = *reinterpret_cast<const float4*>(row + kk * 32);
                float4 v1 = *reinterpret_cast<const float4*>(row + kk * 32 + 4);
                f16x8 a;
                a[0] = (_Float16)v0.x; a[1] = (_Float16)v0.y;
                a[2] = (_Float16)v0.z; a[3] = (_Float16)v0.w;
                a[4] = (_Float16)v1.x; a[5] = (_Float16)v1.y;
                a[6] = (_Float16)v1.z; a[7] = (_Float16)v1.w;
                ax[tile][kk] = a;
            }
        }

        // ---- layer 1 (swapped): h^T tiles; A = W1^T frags, B = x^T frags ----
        f32x4 acc[2][4];
        #pragma unroll
        for (int tile = 0; tile < 2; ++tile)
            #pragma unroll
            for (int nt = 0; nt < 4; ++nt)
                acc[tile][nt] = (f32x4){b1q[nt].x, b1q[nt].y, b1q[nt].z, b1q[nt].w};
        #pragma unroll
        for (int nt = 0; nt < 4; ++nt)
            #pragma unroll
            for (int kk = 0; kk < 4; ++kk) {
                f16x8 bw = sW1[nt * 4 + kk][l];
                acc[0][nt] = mfmaf(bw, ax[0][kk], acc[0][nt]);
                acc[1][nt] = mfmaf(bw, ax[1][kk], acc[1][nt]);
            }

        // ---- swish + in-register transpose to B-frags for layer 2 ----
        f16x8 bf2[2][2];
        #pragma unroll
        for (int tile = 0; tile < 2; ++tile) {
            unsigned pkt[4][2];
            #pragma unroll
            for (int nt = 0; nt < 4; ++nt) {
                float s0 = swishf(acc[tile][nt][0]);
                float s1 = swishf(acc[tile][nt][1]);
                float s2 = swishf(acc[tile][nt][2]);
                float s3 = swishf(acc[tile][nt][3]);
                pkt[nt][0] = pk2(s0, s1);
                pkt[nt][1] = pk2(s2, s3);
            }
            #pragma unroll
            for (int kk2 = 0; kk2 < 2; ++kk2) {
                union { f16x8 v; int w[4]; } fb;
                #pragma unroll
                for (int i = 0; i < 4; ++i) {
                    int src = (((g << 1) + (i >> 1)) & 3) * 16 + n15;
                    int ga = __shfl((int)pkt[2 * kk2][i & 1], src, 64);
                    int gb = __shfl((int)pkt[2 * kk2 + 1][i & 1], src, 64);
                    fb.w[i] = (g < 2) ? ga : gb;
                }
                bf2[tile][kk2] = fb.v;
            }
        }

        // ---- layer 2 (swapped) ----
        f32x4 acc2[2][4];
        #pragma unroll
        for (int tile = 0; tile < 2; ++tile)
            #pragma unroll
            for (int nt = 0; nt < 4; ++nt)
                acc2[tile][nt] = (f32x4){b2q[nt].x, b2q[nt].y, b2q[nt].z, b2q[nt].w};
        #pragma unroll
        for (int nt = 0; nt < 4; ++nt)
            #pragma unroll
            for (int kk = 0; kk < 2; ++kk) {
                f16x8 bw = sW2[nt * 2 + kk][l];
                acc2[0][nt] = mfmaf(bw, bf2[0][kk], acc2[0][nt]);
                acc2[1][nt] = mfmaf(bw, bf2[1][kk], acc2[1][nt]);
            }

        // ---- swish + in-register transpose to B-frags for head ----
        f16x8 bf3[2][2];
        #pragma unroll
        for (int tile = 0; tile < 2; ++tile) {
            unsigned pkt[4][2];
            #pragma unroll
            for (int nt = 0; nt < 4; ++nt) {
                float s0 = swishf(acc2[tile][nt][0]);
                float s1 = swishf(acc2[tile][nt][1]);
                float s2 = swishf(acc2[tile][nt][2]);
                float s3 = swishf(acc2[tile][nt][3]);
                pkt[nt][0] = pk2(s0, s1);
                pkt[nt][1] = pk2(s2, s3);
            }
            #pragma unroll
            for (int kk2 = 0; kk2 < 2; ++kk2) {
                union { f16x8 v; int w[4]; } fb;
                #pragma unroll
                for (int i = 0; i < 4; ++i) {
                    int src = (((g << 1) + (i >> 1)) & 3) * 16 + n15;
                    int ga = __shfl((int)pkt[2 * kk2][i & 1], src, 64);
                    int gb = __shfl((int)pkt[2 * kk2 + 1][i & 1], src, 64);
                    fb.w[i] = (g < 2) ? ga : gb;
                }
                bf3[tile][kk2] = fb.v;
            }
        }

        // ---- head (swapped): D = head^T, lane l reg r = head[l&15][4g+r] ----
        f32x4 ah[2] = {bhq, bhq};
        #pragma unroll
        for (int kk = 0; kk < 2; ++kk) {
            f16x8 bw = sWh[kk][l];
            ah[0] = mfmaf(bw, bf3[0][kk], ah[0]);
            ah[1] = mfmaf(bw, bf3[1][kk], ah[1]);
        }

        if (pass == 1) {
            // v = col 0 = lanes 0..15 reg 0: coalesced 16-lane store
            #pragma unroll
            for (int tile = 0; tile < 2; ++tile)
                if (l < 16)
                    ws_vsp[t0 + tile * 16 + l] = ah[tile][0];
        } else {
            // gather logits cols 1..8 for row n15 via 5 shuffles, then softmax
            #pragma unroll
            for (int tile = 0; tile < 2; ++tile) {
                float c4 = __shfl(ah[tile][0], 16 + n15, 64);
                float c5 = __shfl(ah[tile][1], 16 + n15, 64);
                float c6 = __shfl(ah[tile][2], 16 + n15, 64);
                float c7 = __shfl(ah[tile][3], 16 + n15, 64);
                float c8 = __shfl(ah[tile][0], 32 + n15, 64);
                if (l < 16) {
                    float vs = ah[tile][0];
                    float lgq[A] = {ah[tile][1], ah[tile][2], ah[tile][3],
                                    c4, c5, c6, c7, c8};
                    float m = -1e30f;
                    #pragma unroll
                    for (int q = 0; q < A; ++q) m = fmaxf(m, lgq[q]);
                    float den = 0.f, num = 0.f;
                    #pragma unroll
                    for (int q = 0; q < A; ++q) {
                        float e = __expf(lgq[q] - m);
                        den += e;
                        num = (q == act[mt2][tile]) ? e : num;
                    }
                    int t = t0 + tile * 16 + l;
                    ws_vs[t]  = vs;
                    ws_pia[t] = num / den;
                }
            }
        }
    }
}

// Per-row epilogue: out[t] = -min(surr1,surr2); huber partials per block.
__global__ __launch_bounds__(256) void ppo_epi(
    const float* __restrict__ r, const float* __restrict__ done,
    const float* __restrict__ prob_a,
    const float* __restrict__ ws_vs, const float* __restrict__ ws_pia,
    const float* __restrict__ ws_vsp,
    float* __restrict__ out, float* __restrict__ partial, int Ttot)
{
    __shared__ float sred[256];
    const int tid = threadIdx.x;
    const int t = blockIdx.x * 256 + tid;

    float he = 0.f;
    if (t < Ttot) {
        float vs  = ws_vs[t];
        float vsp = ws_vsp[t];
        float rr  = r[t];
        float dm  = done[t];
        float ratio = ws_pia[t] / prob_a[t];

        float td_target = fmaf(GAMMA * dm, vsp, rr);
        float delta     = rr + GAMMA * vsp - vs;
        float s1 = ratio * delta;
        float rcl = fminf(fmaxf(ratio, 1.0f - EPS_CLIP), 1.0f + EPS_CLIP);
        float s2 = rcl * delta;
        out[t] = -fminf(s1, s2);

        float err = td_target - vs;
        float ae = fabsf(err);
        he = (ae <= 1.0f) ? (0.5f * err * err) : (ae - 0.5f);
    }

    sred[tid] = he;
    __syncthreads();
    #pragma unroll
    for (int off = 128; off > 0; off >>= 1) {
        if (tid < off) sred[tid] += sred[tid + off];
        __syncthreads();
    }
    if (tid == 0) partial[blockIdx.x] = sred[0];
}

// Every block reduces the (L2-resident) partial array to the huber mean, then
// adds it to its own slice of out.
__global__ __launch_bounds__(256) void ppo_finish(
    const float* __restrict__ partial, int nparts, float invT,
    float4* __restrict__ out4, int n4)
{
    __shared__ float sred[256];
    const int tid = threadIdx.x;
    float v = 0.f;
    for (int i = tid; i < nparts; i += 256) v += partial[i];
    sred[tid] = v;
    __syncthreads();
    #pragma unroll
    for (int off = 128; off > 0; off >>= 1) {
        if (tid < off) sred[tid] += sred[tid + off];
        __syncthreads();
    }
    const float m = sred[0] * invT;
    const int i = blockIdx.x * 256 + tid;
    if (i < n4) {
        float4 o = out4[i];
        o.x += m; o.y += m; o.z += m; o.w += m;
        out4[i] = o;
    }
}

extern "C" void kernel_launch(void* const* d_in, const int* in_sizes, int n_in,
                              void* d_out, int out_size, void* d_ws, size_t ws_size,
                              hipStream_t stream)
{
    const float* s      = (const float*)d_in[0];
    const float* sp     = (const float*)d_in[1];
    const float* r      = (const float*)d_in[2];
    const float* done   = (const float*)d_in[3];
    const float* prob_a = (const float*)d_in[4];
    const int*   a      = (const int*)d_in[5];
    const float* W1     = (const float*)d_in[6];
    const float* b1     = (const float*)d_in[7];
    const float* W2     = (const float*)d_in[8];
    const float* b2     = (const float*)d_in[9];
    const float* Wa     = (const float*)d_in[10];
    const float* ba     = (const float*)d_in[11];
    const float* Wc     = (const float*)d_in[12];
    const float* bc     = (const float*)d_in[13];

    float* out = (float*)d_out;
    float* ws  = (float*)d_ws;

    const int Ttot = in_sizes[0] / S;              // 262144
    const int nbf  = Ttot / 512;                   // 512 fwd row-blocks (512 rows each)
    const int nbe  = Ttot / 256;                   // 1024 epi blocks

    float* ws_vs  = ws;
    float* ws_pia = ws + Ttot;
    float* ws_vsp = ws + 2 * (size_t)Ttot;
    float* partial = ws + 3 * (size_t)Ttot;        // nbe floats

    ppo_fwd<<<2 * nbf, 512, 0, stream>>>(s, sp, a, W1, b1, W2, b2, Wa, ba, Wc, bc,
                                         ws_vs, ws_pia, ws_vsp, nbf);
    ppo_epi<<<nbe, 256, 0, stream>>>(r, done, prob_a, ws_vs, ws_pia, ws_vsp,
                                     out, partial, Ttot);

    const int n4 = Ttot / 4;
    ppo_finish<<<(n4 + 255) / 256, 256, 0, stream>>>(partial, nbe,
                                                     1.0f / (float)Ttot,
                                                     (float4*)out, n4);
}